// Round 5
// baseline (258.964 us; speedup 1.0000x reference)
//
#include <hip/hip_runtime.h>
#include <cstdint>
#include <cstddef>

typedef unsigned short ushort_t;
typedef __attribute__((ext_vector_type(8))) short bf16x8;
typedef __attribute__((ext_vector_type(4))) float f32x4;

#define MROWS 16384
#define KDIM  1024
#define NDIM  2048
#define HDIM  512

static __device__ __forceinline__ unsigned short f2bf(float f) {
    unsigned int u = __float_as_uint(f);
    u += 0x7fffu + ((u >> 16) & 1u);   // round-to-nearest-even
    return (unsigned short)(u >> 16);
}

static __device__ __forceinline__ float sigmoid_f(float x) {
    return 1.0f / (1.0f + __expf(-x));
}
static __device__ __forceinline__ float tanh_f(float x) {
    float t = __expf(2.0f * x);
    return 1.0f - 2.0f / (t + 1.0f);   // saturates cleanly at +/-1 for large |x|
}

// ===========================================================================
// Fragment-major layouts (both A and B), so GEMM fragment loads are single
// coalesced dwordx4 per wave (lane-contiguous):
//   chunk(tile, kt, kk, t2, lane) at elem offset
//     (((tile*16 + kt)*2 + kk)*4 + t2)*64*8 + lane*8
//   A: tile = m-wave-tile (64 rows), rows r = t2*16 + (lane&15),
//      k = kt*64 + kk*32 + (lane>>4)*8 .. +8
//   B: tile = n'-tile (64 n' = 16 h), same within-tile mapping, n' = 4h+g
// ===========================================================================

// ---------------------------------------------------------------------------
// Pass 0 (merged): blocks [0,4096): A_sw from concat(x, h_prev)
//                  blocks [4096,4608): B_sw from W_i/W_h with n' = 4h+g perm
// Each block produces one (tile, kt) 8 KB fragment-major unit via LDS.
// ---------------------------------------------------------------------------
__global__ __launch_bounds__(256) void pack_ab(const float* __restrict__ x,
                                               const float* __restrict__ hp,
                                               const float* __restrict__ Wi,
                                               const float* __restrict__ Wh,
                                               ushort_t* __restrict__ A,
                                               ushort_t* __restrict__ B) {
    __shared__ ushort_t sm[64][72];                // 64x64 bf16 tile (+8 pad, keeps 16B align)
    const int tid = threadIdx.x;
    if (blockIdx.x < 4096) {
        // ---- A path: tile wt (64 m-rows) x kt (64 k) ----
        int wt = blockIdx.x >> 4;
        int kt = blockIdx.x & 15;
        int r = tid >> 2;                          // row 0..63
        int c0 = (tid & 3) * 16;                   // col 0..63 step 16
        const float* src = (kt < 8)
            ? (x  + (size_t)(wt * 64 + r) * 512 + kt * 64 + c0)
            : (hp + (size_t)(wt * 64 + r) * 512 + (kt - 8) * 64 + c0);
        float4 v0 = ((const float4*)src)[0];
        float4 v1 = ((const float4*)src)[1];
        float4 v2 = ((const float4*)src)[2];
        float4 v3 = ((const float4*)src)[3];
        ushort_t* d = &sm[r][c0];
        d[0]=f2bf(v0.x); d[1]=f2bf(v0.y); d[2]=f2bf(v0.z); d[3]=f2bf(v0.w);
        d[4]=f2bf(v1.x); d[5]=f2bf(v1.y); d[6]=f2bf(v1.z); d[7]=f2bf(v1.w);
        d[8]=f2bf(v2.x); d[9]=f2bf(v2.y); d[10]=f2bf(v2.z); d[11]=f2bf(v2.w);
        d[12]=f2bf(v3.x); d[13]=f2bf(v3.y); d[14]=f2bf(v3.z); d[15]=f2bf(v3.w);
        __syncthreads();
        ushort_t* outb = A + (size_t)(wt * 16 + kt) * 4096;
#pragma unroll
        for (int i = 0; i < 2; ++i) {
            int c = i * 256 + tid;                 // chunk 0..511
            int lane = c & 63, t2 = (c >> 6) & 3, kk = c >> 8;
            bf16x8 val = *((const bf16x8*)&sm[t2 * 16 + (lane & 15)]
                                             [kk * 32 + (lane >> 4) * 8]);
            *((bf16x8*)(outb + (size_t)c * 8)) = val;
        }
    } else {
        // ---- B path: tile nt (64 n' = 16 h x 4 gates) x kt (64 k) ----
        int b2 = blockIdx.x - 4096;
        int nt = b2 >> 4;                          // 0..31
        int kt = b2 & 15;
        int r = tid >> 2;                          // k row 0..63
        int seg = tid & 3;                         // gate g
        const float* Wsrc = (kt < 8)
            ? (Wi + (size_t)(kt * 64 + r) * NDIM)
            : (Wh + (size_t)((kt - 8) * 64 + r) * NDIM);
        const float* p = Wsrc + seg * 512 + nt * 16;
        float4 q0 = ((const float4*)p)[0];
        float4 q1 = ((const float4*)p)[1];
        float4 q2 = ((const float4*)p)[2];
        float4 q3 = ((const float4*)p)[3];
        float qv[16] = {q0.x,q0.y,q0.z,q0.w, q1.x,q1.y,q1.z,q1.w,
                        q2.x,q2.y,q2.z,q2.w, q3.x,q3.y,q3.z,q3.w};
        // sm layout here: [n'_local][k_local]
#pragma unroll
        for (int j = 0; j < 16; ++j)
            sm[j * 4 + seg][r] = f2bf(qv[j]);
        __syncthreads();
        ushort_t* outb = B + (size_t)(nt * 16 + kt) * 4096;
#pragma unroll
        for (int i = 0; i < 2; ++i) {
            int c = i * 256 + tid;
            int lane = c & 63, t2 = (c >> 6) & 3, kk = c >> 8;
            bf16x8 val = *((const bf16x8*)&sm[t2 * 16 + (lane & 15)]
                                             [kk * 32 + (lane >> 4) * 8]);
            *((bf16x8*)(outb + (size_t)c * 8)) = val;
        }
    }
}

// ---------------------------------------------------------------------------
// Pass 1: barrier-free LDS-free MFMA GEMM. 256x64 block tile, 4 waves each
// owning 64x64. Fragments loaded directly from fragment-major A_sw/B_sw via
// coalesced dwordx4 (B chunks identical across waves -> L1 hits). No
// __syncthreads anywhere; fine-grained vmcnt + TLP hide latency.
// Fused LSTM-cell epilogue through per-wave-private LDS scratch.
// ---------------------------------------------------------------------------
__global__ __launch_bounds__(256, 3) void gemm_cell(const ushort_t* __restrict__ A,
                                                    const ushort_t* __restrict__ B,
                                                    const float* __restrict__ b,
                                                    const float* __restrict__ c_prev,
                                                    float* __restrict__ h_out,
                                                    float* __restrict__ c_out) {
    __shared__ float smem_f[4096];                 // 16 KB epilogue scratch only

    const int tid  = threadIdx.x;
    const int w    = tid >> 6;
    const int lane = tid & 63;
    // XCD-aware swizzle: XCD x owns m-stripes [x*8, x*8+8) across all n
    int bid = blockIdx.x;                          // 2048 blocks
    int lid = (bid >> 3) + (bid & 7) * 256;
    const int mb = lid >> 5;                       // 64 m-blocks (256 rows)
    const int nt = lid & 31;                       // 32 n'-tiles (64 n')
    const int wt = mb * 4 + w;                     // this wave's m-tile (64 rows)
    const int lr   = lane & 15;
    const int quad = lane >> 4;

    const ushort_t* Abase = A + (size_t)wt * 16 * 4096 + lane * 8;
    const ushort_t* Bbase = B + (size_t)nt * 16 * 4096 + lane * 8;

    f32x4 zero = {0.f, 0.f, 0.f, 0.f};
    f32x4 acc[4][4];
#pragma unroll
    for (int i = 0; i < 4; ++i)
#pragma unroll
        for (int j = 0; j < 4; ++j) acc[i][j] = zero;

#pragma unroll 1
    for (int kt = 0; kt < 16; ++kt) {
        const ushort_t* pa = Abase + kt * 4096;
        const ushort_t* pb = Bbase + kt * 4096;
        bf16x8 af[2][4], bf[2][4];
#pragma unroll
        for (int kk = 0; kk < 2; ++kk)
#pragma unroll
            for (int t2 = 0; t2 < 4; ++t2) {
                af[kk][t2] = *((const bf16x8*)(pa + (kk * 4 + t2) * 512));
                bf[kk][t2] = *((const bf16x8*)(pb + (kk * 4 + t2) * 512));
            }
#pragma unroll
        for (int kk = 0; kk < 2; ++kk)
#pragma unroll
            for (int tm = 0; tm < 4; ++tm)
#pragma unroll
                for (int tn = 0; tn < 4; ++tn)
                    acc[tm][tn] = __builtin_amdgcn_mfma_f32_16x16x32_bf16(
                        af[kk][tm], bf[kk][tn], acc[tm][tn], 0, 0, 0);
    }

    // ---- barrier-free epilogue: per-wave private 4 KB scratch ----
    float* scr = smem_f + w * 1024;                // 16 rows x 64 cols
    const int rr = lane >> 2;                      // row within chunk
    const int hg0 = nt * 16 + (lane & 3) * 4;      // 4 consecutive h per lane
    const float4 bi4 = *((const float4*)(b + hg0));
    const float4 bff = *((const float4*)(b + 512 + hg0));
    const float4 bgg = *((const float4*)(b + 1024 + hg0));
    const float4 boo = *((const float4*)(b + 1536 + hg0));
    const float bi[4] = {bi4.x, bi4.y, bi4.z, bi4.w};
    const float bfv[4] = {bff.x, bff.y, bff.z, bff.w};
    const float bg[4] = {bgg.x, bgg.y, bgg.z, bgg.w};
    const float bo[4] = {boo.x, boo.y, boo.z, boo.w};

#pragma unroll
    for (int tm = 0; tm < 4; ++tm) {
        // write 16x64 chunk, XOR-swizzled 16B col-blocks (conflict-free)
#pragma unroll
        for (int tn = 0; tn < 4; ++tn) {
            int c = tn * 16 + lr;
#pragma unroll
            for (int rg = 0; rg < 4; ++rg) {
                int r = quad * 4 + rg;
                int blk = (c >> 2) ^ r;            // 0..15
                scr[r * 64 + blk * 4 + (c & 3)] = acc[tm][tn][rg];
            }
        }
        // same-wave in-order DS pipe: no barrier needed
        float4 gv[4];
#pragma unroll
        for (int j = 0; j < 4; ++j) {
            int cb = (lane & 3) * 4 + j;
            gv[j] = *((const float4*)(scr + rr * 64 + (cb ^ rr) * 4));
        }
        int grow = wt * 64 + tm * 16 + rr;
        float4 cp4 = *((const float4*)(c_prev + (size_t)grow * HDIM + hg0));
        const float cpv[4] = {cp4.x, cp4.y, cp4.z, cp4.w};
        float cn[4], hv[4];
#pragma unroll
        for (int j = 0; j < 4; ++j) {
            float iv = sigmoid_f(gv[j].x + bi[j]);
            float fv = sigmoid_f(gv[j].y + bfv[j]);
            float g2 = tanh_f(gv[j].z + bg[j]);
            float ov = sigmoid_f(gv[j].w + bo[j]);
            cn[j] = fv * cpv[j] + iv * g2;
            hv[j] = ov * tanh_f(cn[j]);
        }
        float4 cno = {cn[0], cn[1], cn[2], cn[3]};
        float4 hvo = {hv[0], hv[1], hv[2], hv[3]};
        *((float4*)(c_out + (size_t)grow * HDIM + hg0)) = cno;
        *((float4*)(h_out + (size_t)grow * HDIM + hg0)) = hvo;
    }
}

// ---------------------------------------------------------------------------
// Pass 2: in-place row-wise LayerNorm on h (one wave per 512-elem row)
// ---------------------------------------------------------------------------
__global__ __launch_bounds__(256) void ln_kernel(float* __restrict__ h,
                                                 const float* __restrict__ lw,
                                                 const float* __restrict__ lb) {
    int w = threadIdx.x >> 6;
    int lane = threadIdx.x & 63;
    int row = blockIdx.x * 4 + w;
    float* p = h + (size_t)row * HDIM + lane * 8;
    float4 a = ((const float4*)p)[0];
    float4 c = ((const float4*)p)[1];
    float s  = a.x + a.y + a.z + a.w + c.x + c.y + c.z + c.w;
    float ss = a.x * a.x + a.y * a.y + a.z * a.z + a.w * a.w +
               c.x * c.x + c.y * c.y + c.z * c.z + c.w * c.w;
#pragma unroll
    for (int off = 32; off > 0; off >>= 1) {
        s  += __shfl_xor(s, off);
        ss += __shfl_xor(ss, off);
    }
    float mu = s * (1.0f / 512.0f);
    float var = ss * (1.0f / 512.0f) - mu * mu;
    float rstd = rsqrtf(var + 1e-5f);
    const float* wp = lw + lane * 8;
    const float* bp = lb + lane * 8;
    float4 w0 = ((const float4*)wp)[0];
    float4 w1 = ((const float4*)wp)[1];
    float4 b0 = ((const float4*)bp)[0];
    float4 b1 = ((const float4*)bp)[1];
    a.x = (a.x - mu) * rstd * w0.x + b0.x;
    a.y = (a.y - mu) * rstd * w0.y + b0.y;
    a.z = (a.z - mu) * rstd * w0.z + b0.z;
    a.w = (a.w - mu) * rstd * w0.w + b0.w;
    c.x = (c.x - mu) * rstd * w1.x + b1.x;
    c.y = (c.y - mu) * rstd * w1.y + b1.y;
    c.z = (c.z - mu) * rstd * w1.z + b1.z;
    c.w = (c.w - mu) * rstd * w1.w + b1.w;
    ((float4*)p)[0] = a;
    ((float4*)p)[1] = c;
}

extern "C" void kernel_launch(void* const* d_in, const int* in_sizes, int n_in,
                              void* d_out, int out_size, void* d_ws, size_t ws_size,
                              hipStream_t stream) {
    const float* x      = (const float*)d_in[0];
    const float* h_prev = (const float*)d_in[1];
    const float* c_prev = (const float*)d_in[2];
    const float* W_i    = (const float*)d_in[3];
    const float* W_h    = (const float*)d_in[4];
    const float* b      = (const float*)d_in[5];
    const float* ln_w   = (const float*)d_in[6];
    const float* ln_b   = (const float*)d_in[7];

    float* h_out = (float*)d_out;                       // [16384][512]
    float* c_out = h_out + (size_t)MROWS * HDIM;        // [16384][512]

    ushort_t* A  = (ushort_t*)d_ws;                     // 32 MB fragment-major
    ushort_t* B  = A + (size_t)MROWS * KDIM;            // 4 MB fragment-major

    pack_ab<<<4096 + 512, 256, 0, stream>>>(x, h_prev, W_i, W_h, A, B);
    gemm_cell<<<2048, 256, 0, stream>>>(A, B, b, c_prev, h_out, c_out);
    ln_kernel<<<MROWS / 4, 256, 0, stream>>>(h_out, ln_w, ln_b);
}